// Round 2
// baseline (1217.979 us; speedup 1.0000x reference)
//
#include <hip/hip_runtime.h>
#include <hip/hip_bf16.h>

// ---------------- problem constants ----------------
#define T_     2048     // tokens (B*S)
#define DIM_   2048
#define INTER_ 1408
#define SH_    2816     // shared inter = 2 * 1408
#define E_     16
#define TOPK_  4

// ---------------- types / helpers ----------------
typedef short bf16x8 __attribute__((ext_vector_type(8)));
typedef short bf16x4 __attribute__((ext_vector_type(4)));
typedef float f32x4  __attribute__((ext_vector_type(4)));

__device__ __forceinline__ short f2bf(float f) {
    unsigned u = __builtin_bit_cast(unsigned, f);
    u = (u + 0x7fffu + ((u >> 16) & 1u)) >> 16;
    return (short)u;
}
__device__ __forceinline__ float bf2f(short s) {
    unsigned u = ((unsigned)(unsigned short)s) << 16;
    return __builtin_bit_cast(float, u);
}
__device__ __forceinline__ f32x4 mfma16(bf16x8 a, bf16x8 b, f32x4 c) {
    return __builtin_amdgcn_mfma_f32_16x16x32_bf16(a, b, c, 0, 0, 0);
}

// Old (fp32-path) LDS layout: [row][48] bf16, slot-XOR swizzle.
#define LDK 48
__device__ __forceinline__ int soff(int r, int slot) {
    return r * LDK + ((slot ^ ((r >> 2) & 3)) << 3);
}
// New (bf16-path) LDS layout: [row][32] bf16 linear rows (global_load_lds
// compatible). Slot swizzle s' = s ^ ((r>>1)&3) applied on the SOURCE
// address at staging and on the slot at fragment-read (involution).
// Bank check (ds_read_b128, 64 lanes): per row r the 4 lk-lanes cover the
// full 64B row; even rows hit banks 0-15, odd rows 16-31 -> 2 lanes/bank.
__device__ __forceinline__ int qoff(int r, int slot) {
    return r * 32 + ((slot ^ ((r >> 1) & 3)) << 3);
}

// async global->LDS, 16B per lane. Dest = wave-uniform base + lane*16.
__device__ __forceinline__ void async_copy16(short* lds, const short* g) {
#if defined(__has_builtin) && __has_builtin(__builtin_amdgcn_global_load_lds)
    __builtin_amdgcn_global_load_lds(
        (const __attribute__((address_space(1))) void*)g,
        (__attribute__((address_space(3))) void*)lds, 16, 0, 0);
#else
    *(bf16x8*)((char*)lds + (size_t)(threadIdx.x & 63) * 16) = *(const bf16x8*)g;
#endif
}

__device__ __forceinline__ bf16x8 pack44(float4 a, float4 b) {
    bf16x8 r;
    r[0] = f2bf(a.x); r[1] = f2bf(a.y); r[2] = f2bf(a.z); r[3] = f2bf(a.w);
    r[4] = f2bf(b.x); r[5] = f2bf(b.y); r[6] = f2bf(b.z); r[7] = f2bf(b.w);
    return r;
}

// ---------------- kernel: zero expert counters ----------------
__global__ void zero_counts_kernel(int* __restrict__ counts) {
    if (threadIdx.x < E_) counts[threadIdx.x] = 0;
}

// ---------------- kernel: weight transpose + bf16 convert ----------------
// src [e][K][N] fp32 -> dst [e][N][K] bf16.  64x64 tiles, 256 threads.
__global__ void transpose_bf16_kernel(const float* __restrict__ src,
                                      short* __restrict__ dst,
                                      int K, int N) {
    src += (size_t)blockIdx.z * K * N;
    dst += (size_t)blockIdx.z * N * K;
    int n0 = blockIdx.x * 64, k0 = blockIdx.y * 64;
    __shared__ short tile[64][66];
    int t = threadIdx.x;
    int hi = t >> 4;            // 0..15
    int c4 = (t & 15) << 2;     // 0,4,..,60
#pragma unroll
    for (int i = 0; i < 4; ++i) {
        int k = i * 16 + hi;
        float4 v = *(const float4*)(src + (size_t)(k0 + k) * N + n0 + c4);
        tile[k][c4 + 0] = f2bf(v.x);
        tile[k][c4 + 1] = f2bf(v.y);
        tile[k][c4 + 2] = f2bf(v.z);
        tile[k][c4 + 3] = f2bf(v.w);
    }
    __syncthreads();
#pragma unroll
    for (int i = 0; i < 4; ++i) {
        int n = i * 16 + hi;
        bf16x4 o;
        o[0] = tile[c4 + 0][n];
        o[1] = tile[c4 + 1][n];
        o[2] = tile[c4 + 2][n];
        o[3] = tile[c4 + 3][n];
        *(bf16x4*)(dst + (size_t)(n0 + n) * K + k0 + c4) = o;
    }
}

// ---------------- kernel: gate + grouped top-k routing ----------------
__global__ void gate_kernel(const float* __restrict__ X,
                            const float* __restrict__ GW,
                            const float* __restrict__ BIAS,
                            int*   __restrict__ counts,
                            int*   __restrict__ ltok,
                            int*   __restrict__ lslot,
                            float* __restrict__ lwt,
                            float* __restrict__ aw) {
    int t = blockIdx.x;
    int lane = threadIdx.x;
    const float* xp = X + (size_t)t * DIM_;
    float acc[E_];
#pragma unroll
    for (int e = 0; e < E_; ++e) acc[e] = 0.f;
    for (int d = lane; d < DIM_; d += 64) {
        float xv = xp[d];
#pragma unroll
        for (int e = 0; e < E_; ++e) acc[e] += xv * GW[e * DIM_ + d];
    }
#pragma unroll
    for (int off = 32; off > 0; off >>= 1) {
#pragma unroll
        for (int e = 0; e < E_; ++e) acc[e] += __shfl_down(acc[e], off, 64);
    }
    if (lane == 0) {
        float orig[E_], s[E_];
#pragma unroll
        for (int e = 0; e < E_; ++e) {
            float sg = 1.f / (1.f + expf(-acc[e]));
            orig[e] = sg;
            s[e] = sg + BIAS[e];
        }
        float gs[4];
#pragma unroll
        for (int g = 0; g < 4; ++g)
            gs[g] = fmaxf(fmaxf(s[4*g], s[4*g+1]), fmaxf(s[4*g+2], s[4*g+3]));
        int g0 = 0;
#pragma unroll
        for (int g = 1; g < 4; ++g) if (gs[g] > gs[g0]) g0 = g;  // lowest idx on tie
        int g1 = -1;
#pragma unroll
        for (int g = 0; g < 4; ++g)
            if (g != g0 && (g1 < 0 || gs[g] > gs[g1])) g1 = g;
        unsigned allow = (0xFu << (g0 * 4)) | (0xFu << (g1 * 4));
        unsigned taken = 0;
        int sel[TOPK_]; float wv[TOPK_]; float wsum = 0.f;
#pragma unroll
        for (int k = 0; k < TOPK_; ++k) {
            int bi = -1; float bv = 0.f;
#pragma unroll
            for (int e = 0; e < E_; ++e) {
                if (((allow >> e) & 1u) && !((taken >> e) & 1u)) {
                    if (bi < 0 || s[e] > bv) { bi = e; bv = s[e]; }
                }
            }
            taken |= 1u << bi;
            sel[k] = bi; wv[k] = orig[bi]; wsum += orig[bi];
        }
        float inv = 1.0f / wsum;    // ROUTE_SCALE = 1.0
#pragma unroll
        for (int k = 0; k < TOPK_; ++k) {
            int e = sel[k];
            float w = wv[k] * inv;
            int pos = atomicAdd(&counts[e], 1);
            ltok [e * T_ + pos] = t;
            lslot[e * T_ + pos] = t * TOPK_ + k;
            lwt  [e * T_ + pos] = w;
            aw[t * TOPK_ + k] = w;
        }
    }
}

// ---------------- SwiGLU GEMM: H = silu(X@W1) * (X@W3) -> bf16 ----------------
// 128x128x32 tile, 4 waves. BF16W: W* are [e][n][k] bf16, staged via
// global_load_lds. !BF16W: W* are [e][k][n] fp32, VGPR-converted.
template<bool GATHER, bool BF16W>
__launch_bounds__(256, 2)
__global__ void swiglu_gemm(const float* __restrict__ X,
                            const void* __restrict__ W1g,
                            const void* __restrict__ W3g,
                            short* __restrict__ Hout,
                            int N, int K,
                            const int* __restrict__ counts,
                            const int* __restrict__ ltok,
                            const int* __restrict__ lslot) {
    int e = GATHER ? blockIdx.z : 0;
    int cnt = GATHER ? counts[e] : (int)(gridDim.y * 128);
    int row_base = blockIdx.y * 128;
    if (row_base >= cnt) return;
    int bn0 = blockIdx.x * 128;

    __shared__ __align__(16) short As [128 * LDK];
    __shared__ __align__(16) short Bs1[128 * LDK];
    __shared__ __align__(16) short Bs3[128 * LDK];

    int t = threadIdx.x;
    // A staging (fp32 x): thread -> (row = t>>1, half = t&1), 16 consecutive k
    int ar = t >> 1, ah = t & 1;
    int arow = row_base + ar;
    bool avalid; int atok;
    if (GATHER) { avalid = arow < cnt; atok = avalid ? ltok[e * T_ + arow] : 0; }
    else        { avalid = true;       atok = arow; }
    const float* aptr = X + (size_t)atok * DIM_ + ah * 16;

    int l = t & 63, wv = t >> 6;
    int wm = (wv >> 1) << 6, wn = (wv & 1) << 6;
    int lr = l & 15, lk = l >> 4;

    const short* bSrc1[2]; const short* bSrc3[2];
    const float* Wf1 = nullptr; const float* Wf3 = nullptr;
    if constexpr (BF16W) {
        const short* Wb1 = (const short*)W1g + (size_t)e * N * K;
        const short* Wb3 = (const short*)W3g + (size_t)e * N * K;
        int r_ = l >> 2, sp = l & 3;
#pragma unroll
        for (int c = 0; c < 2; ++c) {
            int chunk = c * 4 + wv;
            int r = chunk * 16 + r_;
            int ss = sp ^ ((r >> 1) & 3);
            bSrc1[c] = Wb1 + (size_t)(bn0 + r) * K + ss * 8;
            bSrc3[c] = Wb3 + (size_t)(bn0 + r) * K + ss * 8;
        }
    } else {
        Wf1 = (const float*)W1g + (size_t)e * K * N;
        Wf3 = (const float*)W3g + (size_t)e * K * N;
    }

    f32x4 acc1[4][4], acc3[4][4];
    f32x4 z4 = {0.f, 0.f, 0.f, 0.f};
#pragma unroll
    for (int i = 0; i < 4; ++i)
#pragma unroll
        for (int j = 0; j < 4; ++j) { acc1[i][j] = z4; acc3[i][j] = z4; }

    for (int k0 = 0; k0 < K; k0 += 32) {
        // ---- stage A (fp32 -> bf16, VGPR) ----
        float4 v0, v1, v2, v3;
        if (avalid) {
            const float4* p = (const float4*)(aptr + k0);
            v0 = p[0]; v1 = p[1]; v2 = p[2]; v3 = p[3];
        } else {
            v0 = v1 = v2 = v3 = make_float4(0.f, 0.f, 0.f, 0.f);
        }
        *(bf16x8*)&As[soff(ar, ah * 2)]     = pack44(v0, v1);
        *(bf16x8*)&As[soff(ar, ah * 2 + 1)] = pack44(v2, v3);
        // ---- stage B1/B3 ----
        if constexpr (BF16W) {
#pragma unroll
            for (int c = 0; c < 2; ++c) {
                int chunk = c * 4 + wv;
                async_copy16(&Bs1[chunk * 512], bSrc1[c] + k0);
                async_copy16(&Bs3[chunk * 512], bSrc3[c] + k0);
            }
        } else {
            for (int it = t; it < 512; it += 256) {
                int n = it & 127, kc = it >> 7;
                const float* b1p = Wf1 + (size_t)(k0 + kc * 8) * N + bn0 + n;
                const float* b3p = Wf3 + (size_t)(k0 + kc * 8) * N + bn0 + n;
                bf16x8 p1, p3;
#pragma unroll
                for (int j = 0; j < 8; ++j) {
                    p1[j] = f2bf(b1p[(size_t)j * N]);
                    p3[j] = f2bf(b3p[(size_t)j * N]);
                }
                *(bf16x8*)&Bs1[soff(n, kc)] = p1;
                *(bf16x8*)&Bs3[soff(n, kc)] = p3;
            }
        }
        __syncthreads();
        // ---- fragments (all ds_read_b128) + MFMA ----
        bf16x8 af[4], b1f[4], b3f[4];
#pragma unroll
        for (int mf = 0; mf < 4; ++mf)
            af[mf] = *(const bf16x8*)&As[soff(wm + mf * 16 + lr, lk)];
#pragma unroll
        for (int nf = 0; nf < 4; ++nf) {
            int n = wn + nf * 16 + lr;
            if constexpr (BF16W) {
                b1f[nf] = *(const bf16x8*)&Bs1[qoff(n, lk)];
                b3f[nf] = *(const bf16x8*)&Bs3[qoff(n, lk)];
            } else {
                b1f[nf] = *(const bf16x8*)&Bs1[soff(n, lk)];
                b3f[nf] = *(const bf16x8*)&Bs3[soff(n, lk)];
            }
        }
#pragma unroll
        for (int mf = 0; mf < 4; ++mf)
#pragma unroll
            for (int nf = 0; nf < 4; ++nf) {
                acc1[mf][nf] = mfma16(af[mf], b1f[nf], acc1[mf][nf]);
                acc3[mf][nf] = mfma16(af[mf], b3f[nf], acc3[mf][nf]);
            }
        __syncthreads();
    }
    // ---- epilogue: silu(a1)*a3 -> bf16 ----
#pragma unroll
    for (int mf = 0; mf < 4; ++mf)
#pragma unroll
        for (int nf = 0; nf < 4; ++nf)
#pragma unroll
            for (int j = 0; j < 4; ++j) {
                float a1 = acc1[mf][nf][j];
                float a3 = acc3[mf][nf][j];
                float hv = a1 / (1.f + __expf(-a1)) * a3;
                int r = wm + mf * 16 + lk * 4 + j;     // C/D: row=(l>>4)*4+j
                int gr = row_base + r;
                int col = bn0 + wn + nf * 16 + lr;     // C/D: col=l&15
                if (!GATHER || gr < cnt) {
                    size_t orow = GATHER ? (size_t)lslot[(size_t)e * T_ + gr]
                                         : (size_t)gr;
                    Hout[orow * (size_t)N + col] = f2bf(hv);
                }
            }
}

// ---------------- down-proj GEMM: C = H @ W2 (N = DIM_) ----------------
template<bool ROUTED, bool BF16W>
__launch_bounds__(256, 2)
__global__ void out_gemm(const short* __restrict__ Hg,
                         const void* __restrict__ W2g,
                         float* __restrict__ Out,
                         short* __restrict__ Obuf,
                         int K, int use_obuf,
                         const int* __restrict__ counts,
                         const int* __restrict__ lslot,
                         const float* __restrict__ lwt) {
    int e = ROUTED ? blockIdx.z : 0;
    int cnt = ROUTED ? counts[e] : T_;
    int row_base = blockIdx.y * 128;
    if (row_base >= cnt) return;
    int bn0 = blockIdx.x * 128;

    __shared__ __align__(16) short As[128 * LDK];
    __shared__ __align__(16) short Bs[128 * LDK];

    int t = threadIdx.x;
    int l = t & 63, wv = t >> 6;
    int wm = (wv >> 1) << 6, wn = (wv & 1) << 6;
    int lr = l & 15, lk = l >> 4;

    const short* aSrc[2]; const short* bSrc[2];
    const float* Wf2 = nullptr;
    const short* aptr = nullptr; bool avalid = true; int ar = 0, ah = 0;
    if constexpr (BF16W) {
        const short* Wb2 = (const short*)W2g + (size_t)e * (size_t)DIM_ * K;
        int r_ = l >> 2, sp = l & 3;
#pragma unroll
        for (int c = 0; c < 2; ++c) {
            int chunk = c * 4 + wv;
            int r = chunk * 16 + r_;
            int ss = sp ^ ((r >> 1) & 3);
            size_t hrow;
            if constexpr (ROUTED) {
                int gr = row_base + r;
                hrow = (size_t)((gr < cnt) ? lslot[(size_t)e * T_ + gr] : 0);
            } else {
                hrow = (size_t)(row_base + r);
            }
            aSrc[c] = Hg + hrow * K + ss * 8;
            bSrc[c] = Wb2 + (size_t)(bn0 + r) * K + ss * 8;
        }
    } else {
        Wf2 = (const float*)W2g + (size_t)e * K * DIM_;
        ar = t >> 1; ah = t & 1;
        int arow = row_base + ar;
        if constexpr (ROUTED) {
            avalid = arow < cnt;
            aptr = avalid ? Hg + (size_t)lslot[(size_t)e * T_ + arow] * K + ah * 16 : Hg;
        } else {
            aptr = Hg + (size_t)arow * K + ah * 16;
        }
    }

    f32x4 acc[4][4];
    f32x4 z4 = {0.f, 0.f, 0.f, 0.f};
#pragma unroll
    for (int i = 0; i < 4; ++i)
#pragma unroll
        for (int j = 0; j < 4; ++j) acc[i][j] = z4;

    for (int k0 = 0; k0 < K; k0 += 32) {
        if constexpr (BF16W) {
#pragma unroll
            for (int c = 0; c < 2; ++c) {
                int chunk = c * 4 + wv;
                async_copy16(&As[chunk * 512], aSrc[c] + k0);
                async_copy16(&Bs[chunk * 512], bSrc[c] + k0);
            }
        } else {
            bf16x8 pa0, pa1;
            if (avalid) {
                pa0 = *(const bf16x8*)(aptr + k0);
                pa1 = *(const bf16x8*)(aptr + k0 + 8);
            } else {
#pragma unroll
                for (int j = 0; j < 8; ++j) { pa0[j] = 0; pa1[j] = 0; }
            }
            *(bf16x8*)&As[soff(ar, ah * 2)]     = pa0;
            *(bf16x8*)&As[soff(ar, ah * 2 + 1)] = pa1;
            for (int it = t; it < 512; it += 256) {
                int n = it & 127, kc = it >> 7;
                const float* bp = Wf2 + (size_t)(k0 + kc * 8) * DIM_ + bn0 + n;
                bf16x8 p;
#pragma unroll
                for (int j = 0; j < 8; ++j) p[j] = f2bf(bp[(size_t)j * DIM_]);
                *(bf16x8*)&Bs[soff(n, kc)] = p;
            }
        }
        __syncthreads();
        bf16x8 af[4], bfr[4];
#pragma unroll
        for (int mf = 0; mf < 4; ++mf) {
            int r = wm + mf * 16 + lr;
            if constexpr (BF16W) af[mf] = *(const bf16x8*)&As[qoff(r, lk)];
            else                 af[mf] = *(const bf16x8*)&As[soff(r, lk)];
        }
#pragma unroll
        for (int nf = 0; nf < 4; ++nf) {
            int n = wn + nf * 16 + lr;
            if constexpr (BF16W) bfr[nf] = *(const bf16x8*)&Bs[qoff(n, lk)];
            else                 bfr[nf] = *(const bf16x8*)&Bs[soff(n, lk)];
        }
#pragma unroll
        for (int mf = 0; mf < 4; ++mf)
#pragma unroll
            for (int nf = 0; nf < 4; ++nf)
                acc[mf][nf] = mfma16(af[mf], bfr[nf], acc[mf][nf]);
        __syncthreads();
    }
#pragma unroll
    for (int mf = 0; mf < 4; ++mf)
#pragma unroll
        for (int nf = 0; nf < 4; ++nf)
#pragma unroll
            for (int j = 0; j < 4; ++j) {
                float v = acc[mf][nf][j];
                int r = wm + mf * 16 + lk * 4 + j;
                int gr = row_base + r;
                int col = bn0 + wn + nf * 16 + lr;
                if constexpr (ROUTED) {
                    if (gr < cnt) {
                        int a = lslot[(size_t)e * T_ + gr];
                        if (use_obuf) {
                            Obuf[(size_t)a * DIM_ + col] = f2bf(v);
                        } else {
                            float w = lwt[(size_t)e * T_ + gr];
                            atomicAdd(&Out[(size_t)(a >> 2) * DIM_ + col], v * w);
                        }
                    }
                } else {
                    Out[(size_t)gr * DIM_ + col] = v;   // z written first
                }
            }
}

// ---------------- combine: out[t] += sum_k w_k * obuf[t*4+k] ----------------
__global__ void combine_kernel(const short* __restrict__ Obuf,
                               const float* __restrict__ aw,
                               float* __restrict__ Out) {
    int t = blockIdx.x;
    int c0 = threadIdx.x << 3;
    float s[8];
#pragma unroll
    for (int j = 0; j < 8; ++j) s[j] = 0.f;
#pragma unroll
    for (int k = 0; k < TOPK_; ++k) {
        float w = aw[t * TOPK_ + k];
        const short* rp = Obuf + ((size_t)(t * TOPK_ + k)) * DIM_ + c0;
#pragma unroll
        for (int j = 0; j < 8; ++j) s[j] += w * bf2f(rp[j]);
    }
    float* op = Out + (size_t)t * DIM_ + c0;
#pragma unroll
    for (int j = 0; j < 8; ++j) op[j] += s[j];
}

// ---------------- launch ----------------
extern "C" void kernel_launch(void* const* d_in, const int* in_sizes, int n_in,
                              void* d_out, int out_size, void* d_ws, size_t ws_size,
                              hipStream_t stream) {
    const float* x     = (const float*)d_in[0];
    const float* gw    = (const float*)d_in[1];
    const float* ebias = (const float*)d_in[2];
    const float* w1    = (const float*)d_in[3];
    const float* w2    = (const float*)d_in[4];
    const float* w3    = (const float*)d_in[5];
    const float* sw1   = (const float*)d_in[6];
    const float* sw2   = (const float*)d_in[7];
    const float* sw3   = (const float*)d_in[8];
    float* out = (float*)d_out;

    char* wsb = (char*)d_ws;
    int*   counts = (int*)wsb;                                    // 64 B
    int*   ltok   = (int*)(wsb + 1024);                           // 128 KB
    int*   lslot  = (int*)(wsb + 1024 + 131072);                  // 128 KB
    float* lwt    = (float*)(wsb + 1024 + 2 * 131072);            // 128 KB
    float* aw     = (float*)(wsb + 1024 + 3 * 131072);            // 32 KB
    size_t off = 1024 + 3 * 131072 + 32768;                       // 427008
    short* hbuf = (short*)(wsb + off);
    size_t hbuf_sz = (size_t)T_ * TOPK_ * INTER_ * 2;             // 23.07 MB
    size_t obuf_sz = (size_t)T_ * TOPK_ * DIM_ * 2;               // 33.55 MB
    size_t hs_sz   = (size_t)T_ * SH_ * 2;                        // 11.53 MB
    size_t wt_sz   = (size_t)E_ * INTER_ * DIM_ * 2;              // 92.27 MB
    size_t swt_sz  = (size_t)SH_ * DIM_ * 2;                      // 11.53 MB

    size_t need_fp32a = off + hbuf_sz + hs_sz;                    // atomic path
    size_t need_fp32  = need_fp32a + obuf_sz;                     // fp32 + obuf
    size_t need_bf16  = need_fp32 + 3 * wt_sz + 3 * swt_sz;       // + bf16 weights

    size_t o2 = off + hbuf_sz;
    short* obuf = (short*)(wsb + o2);
    int use_obuf = (ws_size >= need_fp32) ? 1 : 0;
    if (use_obuf) o2 += obuf_sz;
    short* hs = (short*)(wsb + o2); o2 += hs_sz;
    short* wt1  = (short*)(wsb + o2); o2 += wt_sz;
    short* wt3  = (short*)(wsb + o2); o2 += wt_sz;
    short* wt2  = (short*)(wsb + o2); o2 += wt_sz;
    short* swt1 = (short*)(wsb + o2); o2 += swt_sz;
    short* swt3 = (short*)(wsb + o2); o2 += swt_sz;
    short* swt2 = (short*)(wsb + o2);
    int bf16w = (ws_size >= need_bf16) ? 1 : 0;

    zero_counts_kernel<<<1, 64, 0, stream>>>(counts);
    gate_kernel<<<T_, 64, 0, stream>>>(x, gw, ebias, counts, ltok, lslot, lwt, aw);

    if (bf16w) {
        // weight prepass: [K][N] fp32 -> [N][K] bf16
        transpose_bf16_kernel<<<dim3(INTER_/64, DIM_/64, E_), 256, 0, stream>>>(w1, wt1, DIM_, INTER_);
        transpose_bf16_kernel<<<dim3(INTER_/64, DIM_/64, E_), 256, 0, stream>>>(w3, wt3, DIM_, INTER_);
        transpose_bf16_kernel<<<dim3(DIM_/64, INTER_/64, E_), 256, 0, stream>>>(w2, wt2, INTER_, DIM_);
        transpose_bf16_kernel<<<dim3(SH_/64, DIM_/64, 1), 256, 0, stream>>>(sw1, swt1, DIM_, SH_);
        transpose_bf16_kernel<<<dim3(SH_/64, DIM_/64, 1), 256, 0, stream>>>(sw3, swt3, DIM_, SH_);
        transpose_bf16_kernel<<<dim3(DIM_/64, SH_/64, 1), 256, 0, stream>>>(sw2, swt2, SH_, DIM_);

        swiglu_gemm<false, true><<<dim3(SH_/128, T_/128), 256, 0, stream>>>(
            x, swt1, swt3, hs, SH_, DIM_, nullptr, nullptr, nullptr);
        out_gemm<false, true><<<dim3(DIM_/128, T_/128), 256, 0, stream>>>(
            hs, swt2, out, nullptr, SH_, 0, nullptr, nullptr, nullptr);
        swiglu_gemm<true, true><<<dim3(INTER_/128, T_/128, E_), 256, 0, stream>>>(
            x, wt1, wt3, hbuf, INTER_, DIM_, counts, ltok, lslot);
        out_gemm<true, true><<<dim3(DIM_/128, T_/128, E_), 256, 0, stream>>>(
            hbuf, wt2, out, obuf, INTER_, 1, counts, lslot, lwt);
        combine_kernel<<<T_, 256, 0, stream>>>(obuf, aw, out);
    } else {
        swiglu_gemm<false, false><<<dim3(SH_/128, T_/128), 256, 0, stream>>>(
            x, sw1, sw3, hs, SH_, DIM_, nullptr, nullptr, nullptr);
        out_gemm<false, false><<<dim3(DIM_/128, T_/128), 256, 0, stream>>>(
            hs, sw2, out, nullptr, SH_, 0, nullptr, nullptr, nullptr);
        swiglu_gemm<true, false><<<dim3(INTER_/128, T_/128, E_), 256, 0, stream>>>(
            x, w1, w3, hbuf, INTER_, DIM_, counts, ltok, lslot);
        out_gemm<true, false><<<dim3(DIM_/128, T_/128, E_), 256, 0, stream>>>(
            hbuf, w2, out, obuf, INTER_, use_obuf, counts, lslot, lwt);
        if (use_obuf)
            combine_kernel<<<T_, 256, 0, stream>>>(obuf, aw, out);
    }
}

// Round 3
// 1164.955 us; speedup vs baseline: 1.0455x; 1.0455x over previous
//
#include <hip/hip_runtime.h>
#include <hip/hip_bf16.h>

// ---------------- problem constants ----------------
#define T_     2048     // tokens (B*S)
#define DIM_   2048
#define INTER_ 1408
#define SH_    2816     // shared inter = 2 * 1408
#define E_     16
#define TOPK_  4

// ---------------- types / helpers ----------------
typedef short bf16x8 __attribute__((ext_vector_type(8)));
typedef short bf16x4 __attribute__((ext_vector_type(4)));
typedef float f32x4  __attribute__((ext_vector_type(4)));

__device__ __forceinline__ short f2bf(float f) {
    unsigned u = __builtin_bit_cast(unsigned, f);
    u = (u + 0x7fffu + ((u >> 16) & 1u)) >> 16;
    return (short)u;
}
__device__ __forceinline__ float bf2f(short s) {
    unsigned u = ((unsigned)(unsigned short)s) << 16;
    return __builtin_bit_cast(float, u);
}
__device__ __forceinline__ f32x4 mfma16(bf16x8 a, bf16x8 b, f32x4 c) {
    return __builtin_amdgcn_mfma_f32_16x16x32_bf16(a, b, c, 0, 0, 0);
}
__device__ __forceinline__ bf16x8 pack44(float4 a, float4 b) {
    bf16x8 r;
    r[0] = f2bf(a.x); r[1] = f2bf(a.y); r[2] = f2bf(a.z); r[3] = f2bf(a.w);
    r[4] = f2bf(b.x); r[5] = f2bf(b.y); r[6] = f2bf(b.z); r[7] = f2bf(b.w);
    return r;
}

// LDS tile [row][32] bf16, linear rows (global_load_lds-compatible).
// Slot swizzle s' = s ^ ((r>>1)&3) applied on SOURCE address at staging and
// on the slot at fragment read (involution; both-sides rule). ds_read_b128
// fragment reads land 2 lanes/bank (free per m136).
__device__ __forceinline__ int qoff(int r, int slot) {
    return r * 32 + ((slot ^ ((r >> 1) & 3)) << 3);
}

// async global->LDS, 16B/lane. LDS dest = wave-uniform base + lane*16.
__device__ __forceinline__ void async_copy16(short* lds, const short* g) {
    __builtin_amdgcn_global_load_lds(
        (const __attribute__((address_space(1))) void*)g,
        (__attribute__((address_space(3))) void*)lds, 16, 0, 0);
}

// ---------------- zero expert counters ----------------
__global__ void zero_counts_kernel(int* __restrict__ counts) {
    if (threadIdx.x < E_) counts[threadIdx.x] = 0;
}

// ---------------- x -> bf16 (same RNE as in-GEMM convert) ----------------
__global__ void xconv_kernel(const float* __restrict__ x, short* __restrict__ xb) {
    size_t i = ((size_t)blockIdx.x * 256 + threadIdx.x) * 8;
    float4 a = *(const float4*)(x + i);
    float4 b = *(const float4*)(x + i + 4);
    *(bf16x8*)(xb + i) = pack44(a, b);
}

// ---------------- weight transpose + bf16: [z][K][N] f32 -> [z][N][K] bf16 ----------------
__global__ void transpose_bf16_kernel(const float* __restrict__ src,
                                      short* __restrict__ dst,
                                      int K, int N) {
    src += (size_t)blockIdx.z * K * N;
    dst += (size_t)blockIdx.z * N * K;
    int n0 = blockIdx.x * 64, k0 = blockIdx.y * 64;
    __shared__ short tile[64][66];
    int t = threadIdx.x;
    int hi = t >> 4;            // 0..15
    int c4 = (t & 15) << 2;     // 0,4,..,60
#pragma unroll
    for (int i = 0; i < 4; ++i) {
        int k = i * 16 + hi;
        float4 v = *(const float4*)(src + (size_t)(k0 + k) * N + n0 + c4);
        tile[k][c4 + 0] = f2bf(v.x);
        tile[k][c4 + 1] = f2bf(v.y);
        tile[k][c4 + 2] = f2bf(v.z);
        tile[k][c4 + 3] = f2bf(v.w);
    }
    __syncthreads();
    // write phase: b128 per lane; 8 lanes cover 128B contiguous in dst
    int n_ = t >> 3, kg = t & 7;
#pragma unroll
    for (int p = 0; p < 2; ++p) {
        int n = p * 32 + n_;
        bf16x8 o;
#pragma unroll
        for (int j = 0; j < 8; ++j) o[j] = tile[kg * 8 + j][n];
        *(bf16x8*)(dst + (size_t)(n0 + n) * K + k0 + kg * 8) = o;
    }
}

// ---------------- gate + grouped top-k routing (exact fp32) ----------------
__global__ void gate_kernel(const float* __restrict__ X,
                            const float* __restrict__ GW,
                            const float* __restrict__ BIAS,
                            int*   __restrict__ counts,
                            int*   __restrict__ ltok,
                            int*   __restrict__ lslot,
                            float* __restrict__ lwt,
                            float* __restrict__ aw) {
    int t = blockIdx.x;
    int lane = threadIdx.x;
    const float* xp = X + (size_t)t * DIM_;
    float acc[E_];
#pragma unroll
    for (int e = 0; e < E_; ++e) acc[e] = 0.f;
    for (int d = lane; d < DIM_; d += 64) {
        float xv = xp[d];
#pragma unroll
        for (int e = 0; e < E_; ++e) acc[e] += xv * GW[e * DIM_ + d];
    }
#pragma unroll
    for (int off = 32; off > 0; off >>= 1) {
#pragma unroll
        for (int e = 0; e < E_; ++e) acc[e] += __shfl_down(acc[e], off, 64);
    }
    if (lane == 0) {
        float orig[E_], s[E_];
#pragma unroll
        for (int e = 0; e < E_; ++e) {
            float sg = 1.f / (1.f + expf(-acc[e]));
            orig[e] = sg;
            s[e] = sg + BIAS[e];
        }
        float gs[4];
#pragma unroll
        for (int g = 0; g < 4; ++g)
            gs[g] = fmaxf(fmaxf(s[4*g], s[4*g+1]), fmaxf(s[4*g+2], s[4*g+3]));
        int g0 = 0;
#pragma unroll
        for (int g = 1; g < 4; ++g) if (gs[g] > gs[g0]) g0 = g;  // lowest idx on tie
        int g1 = -1;
#pragma unroll
        for (int g = 0; g < 4; ++g)
            if (g != g0 && (g1 < 0 || gs[g] > gs[g1])) g1 = g;
        unsigned allow = (0xFu << (g0 * 4)) | (0xFu << (g1 * 4));
        unsigned taken = 0;
        int sel[TOPK_]; float wv[TOPK_]; float wsum = 0.f;
#pragma unroll
        for (int k = 0; k < TOPK_; ++k) {
            int bi = -1; float bv = 0.f;
#pragma unroll
            for (int e = 0; e < E_; ++e) {
                if (((allow >> e) & 1u) && !((taken >> e) & 1u)) {
                    if (bi < 0 || s[e] > bv) { bi = e; bv = s[e]; }
                }
            }
            taken |= 1u << bi;
            sel[k] = bi; wv[k] = orig[bi]; wsum += orig[bi];
        }
        float inv = 1.0f / wsum;    // ROUTE_SCALE = 1.0
#pragma unroll
        for (int k = 0; k < TOPK_; ++k) {
            int e = sel[k];
            float w = wv[k] * inv;
            int pos = atomicAdd(&counts[e], 1);
            ltok [e * T_ + pos] = t;
            lslot[e * T_ + pos] = t * TOPK_ + k;
            lwt  [e * T_ + pos] = w;
            aw[t * TOPK_ + k] = w;
        }
    }
}

// ---------------- SwiGLU GEMM: H = silu(Xb@W1)*(Xb@W3) -> bf16 ----------------
// 128x128x32 tile, 4 waves, double-buffered 2-phase pipeline: issue next-tile
// global_load_lds BEFORE computing current tile; ONE barrier per K-step
// (its implicit vmcnt(0) drains the prefetch -> T3-minimum schedule).
template<bool GATHER>
__launch_bounds__(256, 2)
__global__ void swiglu_gemm2(const short* __restrict__ Xb,
                             const short* __restrict__ W1g,
                             const short* __restrict__ W3g,
                             short* __restrict__ Hout,
                             int N, int K,
                             const int* __restrict__ counts,
                             const int* __restrict__ ltok,
                             const int* __restrict__ lslot) {
    int e = GATHER ? blockIdx.z : 0;
    int cnt = GATHER ? counts[e] : (int)(gridDim.y * 128);
    int row_base = blockIdx.y * 128;
    if (row_base >= cnt) return;
    int bn0 = blockIdx.x * 128;
    const short* W1 = W1g + (size_t)e * N * K;
    const short* W3 = W3g + (size_t)e * N * K;

    __shared__ __align__(16) short As [2][4096];   // 128 rows x 32 k, x2 buf
    __shared__ __align__(16) short Bs1[2][4096];
    __shared__ __align__(16) short Bs3[2][4096];

    int t = threadIdx.x, l = t & 63, wv = t >> 6;
    int wm = (wv >> 1) << 6, wn = (wv & 1) << 6;
    int lr = l & 15, lk = l >> 4;
    int r_ = l >> 2, sp = l & 3;

    // staging source pointers (source-side inverse swizzle; LDS stays linear)
    const short *aS[2], *b1S[2], *b3S[2];
#pragma unroll
    for (int c = 0; c < 2; ++c) {
        int chunk = c * 4 + wv;
        int r = chunk * 16 + r_;
        int ss = sp ^ ((r >> 1) & 3);
        int grow = row_base + r;
        int tok;
        if constexpr (GATHER) {
            int ci = grow < cnt ? grow : cnt - 1;
            tok = ltok[e * T_ + ci];
        } else tok = grow;
        aS [c] = Xb + (size_t)tok * K + ss * 8;
        b1S[c] = W1 + (size_t)(bn0 + r) * K + ss * 8;
        b3S[c] = W3 + (size_t)(bn0 + r) * K + ss * 8;
    }

    f32x4 acc1[4][4], acc3[4][4];
    f32x4 z4 = {0.f, 0.f, 0.f, 0.f};
#pragma unroll
    for (int i = 0; i < 4; ++i)
#pragma unroll
        for (int j = 0; j < 4; ++j) { acc1[i][j] = z4; acc3[i][j] = z4; }

    int nt = K >> 5;
    // prologue
#pragma unroll
    for (int c = 0; c < 2; ++c) {
        int chunk = c * 4 + wv;
        async_copy16(&As [0][chunk * 512], aS [c]);
        async_copy16(&Bs1[0][chunk * 512], b1S[c]);
        async_copy16(&Bs3[0][chunk * 512], b3S[c]);
    }
    __syncthreads();
    int cur = 0;
    for (int kt = 0; kt < nt; ++kt) {
        if (kt + 1 < nt) {
            int k0 = (kt + 1) << 5;
#pragma unroll
            for (int c = 0; c < 2; ++c) {
                int chunk = c * 4 + wv;
                async_copy16(&As [cur ^ 1][chunk * 512], aS [c] + k0);
                async_copy16(&Bs1[cur ^ 1][chunk * 512], b1S[c] + k0);
                async_copy16(&Bs3[cur ^ 1][chunk * 512], b3S[c] + k0);
            }
        }
        bf16x8 af[4], b1f[4], b3f[4];
#pragma unroll
        for (int mf = 0; mf < 4; ++mf)
            af[mf] = *(const bf16x8*)&As[cur][qoff(wm + mf * 16 + lr, lk)];
#pragma unroll
        for (int nf = 0; nf < 4; ++nf) {
            int n = wn + nf * 16 + lr;
            b1f[nf] = *(const bf16x8*)&Bs1[cur][qoff(n, lk)];
            b3f[nf] = *(const bf16x8*)&Bs3[cur][qoff(n, lk)];
        }
#pragma unroll
        for (int mf = 0; mf < 4; ++mf)
#pragma unroll
            for (int nf = 0; nf < 4; ++nf) {
                acc1[mf][nf] = mfma16(af[mf], b1f[nf], acc1[mf][nf]);
                acc3[mf][nf] = mfma16(af[mf], b3f[nf], acc3[mf][nf]);
            }
        __syncthreads();   // drains prefetch (vmcnt 0) + guards buffer reuse
        cur ^= 1;
    }
    // epilogue: silu(a1)*a3 -> bf16
#pragma unroll
    for (int mf = 0; mf < 4; ++mf)
#pragma unroll
        for (int nf = 0; nf < 4; ++nf)
#pragma unroll
            for (int j = 0; j < 4; ++j) {
                float a1 = acc1[mf][nf][j];
                float a3 = acc3[mf][nf][j];
                float hv = a1 / (1.f + __expf(-a1)) * a3;
                int r = wm + mf * 16 + lk * 4 + j;     // C/D: row=(l>>4)*4+j
                int gr = row_base + r;
                int col = bn0 + wn + nf * 16 + lr;     // C/D: col=l&15
                if (!GATHER || gr < cnt) {
                    size_t orow = GATHER ? (size_t)lslot[(size_t)e * T_ + gr]
                                         : (size_t)gr;
                    Hout[orow * (size_t)N + col] = f2bf(hv);
                }
            }
}

// ---------------- down-proj GEMM: C = H @ W2 (N = DIM_) ----------------
// ROUTED: H rows gathered by slot, store bf16 to Obuf[slot].
// !ROUTED (+COMBINE): Out[t] = z + sum_k aw[t,k]*Obuf[t*4+k]  (fused combine)
template<bool ROUTED, bool COMBINE>
__launch_bounds__(256, 3)
__global__ void out_gemm2(const short* __restrict__ Hg,
                          const short* __restrict__ W2g,
                          float* __restrict__ Out,
                          short* __restrict__ Obuf,
                          const float* __restrict__ aw,
                          int K,
                          const int* __restrict__ counts,
                          const int* __restrict__ lslot) {
    int e = ROUTED ? blockIdx.z : 0;
    int cnt = ROUTED ? counts[e] : T_;
    int row_base = blockIdx.y * 128;
    if (row_base >= cnt) return;
    int bn0 = blockIdx.x * 128;
    const short* W2 = W2g + (size_t)e * (size_t)DIM_ * K;

    __shared__ __align__(16) short As[2][4096];
    __shared__ __align__(16) short Bs[2][4096];

    int t = threadIdx.x, l = t & 63, wv = t >> 6;
    int wm = (wv >> 1) << 6, wn = (wv & 1) << 6;
    int lr = l & 15, lk = l >> 4;
    int r_ = l >> 2, sp = l & 3;

    const short *aS[2], *bS[2];
#pragma unroll
    for (int c = 0; c < 2; ++c) {
        int chunk = c * 4 + wv;
        int r = chunk * 16 + r_;
        int ss = sp ^ ((r >> 1) & 3);
        size_t hrow;
        if constexpr (ROUTED) {
            int grow = row_base + r;
            int ci = grow < cnt ? grow : cnt - 1;
            hrow = (size_t)lslot[(size_t)e * T_ + ci];
        } else {
            hrow = (size_t)(row_base + r);
        }
        aS[c] = Hg + hrow * K + ss * 8;
        bS[c] = W2 + (size_t)(bn0 + r) * K + ss * 8;
    }

    f32x4 acc[4][4];
    f32x4 z4 = {0.f, 0.f, 0.f, 0.f};
#pragma unroll
    for (int i = 0; i < 4; ++i)
#pragma unroll
        for (int j = 0; j < 4; ++j) acc[i][j] = z4;

    int nt = K >> 5;
#pragma unroll
    for (int c = 0; c < 2; ++c) {
        int chunk = c * 4 + wv;
        async_copy16(&As[0][chunk * 512], aS[c]);
        async_copy16(&Bs[0][chunk * 512], bS[c]);
    }
    __syncthreads();
    int cur = 0;
    for (int kt = 0; kt < nt; ++kt) {
        if (kt + 1 < nt) {
            int k0 = (kt + 1) << 5;
#pragma unroll
            for (int c = 0; c < 2; ++c) {
                int chunk = c * 4 + wv;
                async_copy16(&As[cur ^ 1][chunk * 512], aS[c] + k0);
                async_copy16(&Bs[cur ^ 1][chunk * 512], bS[c] + k0);
            }
        }
        bf16x8 af[4], bfr[4];
#pragma unroll
        for (int mf = 0; mf < 4; ++mf)
            af[mf] = *(const bf16x8*)&As[cur][qoff(wm + mf * 16 + lr, lk)];
#pragma unroll
        for (int nf = 0; nf < 4; ++nf)
            bfr[nf] = *(const bf16x8*)&Bs[cur][qoff(wn + nf * 16 + lr, lk)];
#pragma unroll
        for (int mf = 0; mf < 4; ++mf)
#pragma unroll
            for (int nf = 0; nf < 4; ++nf)
                acc[mf][nf] = mfma16(af[mf], bfr[nf], acc[mf][nf]);
        __syncthreads();
        cur ^= 1;
    }
#pragma unroll
    for (int mf = 0; mf < 4; ++mf)
#pragma unroll
        for (int nf = 0; nf < 4; ++nf)
#pragma unroll
            for (int j = 0; j < 4; ++j) {
                float v = acc[mf][nf][j];
                int r = wm + mf * 16 + lk * 4 + j;
                int gr = row_base + r;
                int col = bn0 + wn + nf * 16 + lr;
                if constexpr (ROUTED) {
                    if (gr < cnt) {
                        int a = lslot[(size_t)e * T_ + gr];
                        Obuf[(size_t)a * DIM_ + col] = f2bf(v);
                    }
                } else {
                    float o = v;
                    if constexpr (COMBINE) {
#pragma unroll
                        for (int k = 0; k < TOPK_; ++k) {
                            float w = aw[gr * TOPK_ + k];
                            o += w * bf2f(Obuf[(size_t)(gr * TOPK_ + k) * DIM_ + col]);
                        }
                    }
                    Out[(size_t)gr * DIM_ + col] = o;
                }
            }
}

// ---------------- launch ----------------
// ws layout (all rewritten every call; harness poisons ws with 0xAA):
// counts 1KB | ltok/lslot/lwt 3x128KB | aw 32KB | xb 8.39MB | hbuf 23.07MB |
// obuf 33.55MB | hs 11.53MB | wt1/wt3/wt2 3x92.27MB | swt1/swt3/swt2 3x11.53MB
// total ~388.4MB (round-2 bench proved ws >= 381MB; assuming >= 389MB).
extern "C" void kernel_launch(void* const* d_in, const int* in_sizes, int n_in,
                              void* d_out, int out_size, void* d_ws, size_t ws_size,
                              hipStream_t stream) {
    const float* x     = (const float*)d_in[0];
    const float* gw    = (const float*)d_in[1];
    const float* ebias = (const float*)d_in[2];
    const float* w1    = (const float*)d_in[3];
    const float* w2    = (const float*)d_in[4];
    const float* w3    = (const float*)d_in[5];
    const float* sw1   = (const float*)d_in[6];
    const float* sw2   = (const float*)d_in[7];
    const float* sw3   = (const float*)d_in[8];
    float* out = (float*)d_out;

    char* wsb = (char*)d_ws;
    size_t o = 0;
    int*   counts = (int*)(wsb + o);  o += 1024;
    int*   ltok   = (int*)(wsb + o);  o += 131072;
    int*   lslot  = (int*)(wsb + o);  o += 131072;
    float* lwt    = (float*)(wsb + o); o += 131072;
    float* aw     = (float*)(wsb + o); o += 32768;
    short* xb   = (short*)(wsb + o);  o += (size_t)T_ * DIM_ * 2;
    short* hbuf = (short*)(wsb + o);  o += (size_t)T_ * TOPK_ * INTER_ * 2;
    short* obuf = (short*)(wsb + o);  o += (size_t)T_ * TOPK_ * DIM_ * 2;
    short* hs   = (short*)(wsb + o);  o += (size_t)T_ * SH_ * 2;
    short* wt1  = (short*)(wsb + o);  o += (size_t)E_ * INTER_ * DIM_ * 2;
    short* wt3  = (short*)(wsb + o);  o += (size_t)E_ * INTER_ * DIM_ * 2;
    short* wt2  = (short*)(wsb + o);  o += (size_t)E_ * INTER_ * DIM_ * 2;
    short* swt1 = (short*)(wsb + o);  o += (size_t)SH_ * DIM_ * 2;
    short* swt3 = (short*)(wsb + o);  o += (size_t)SH_ * DIM_ * 2;
    short* swt2 = (short*)(wsb + o);

    zero_counts_kernel<<<1, 64, 0, stream>>>(counts);
    gate_kernel<<<T_, 64, 0, stream>>>(x, gw, ebias, counts, ltok, lslot, lwt, aw);
    xconv_kernel<<<(T_ * DIM_) / (256 * 8), 256, 0, stream>>>(x, xb);

    // --- routed path, ordered for L3 residency of freshly-written weights ---
    transpose_bf16_kernel<<<dim3(INTER_/64, DIM_/64, E_), 256, 0, stream>>>(w1, wt1, DIM_, INTER_);
    transpose_bf16_kernel<<<dim3(INTER_/64, DIM_/64, E_), 256, 0, stream>>>(w3, wt3, DIM_, INTER_);
    swiglu_gemm2<true><<<dim3(INTER_/128, T_/128, E_), 256, 0, stream>>>(
        xb, wt1, wt3, hbuf, INTER_, DIM_, counts, ltok, lslot);
    transpose_bf16_kernel<<<dim3(DIM_/64, INTER_/64, E_), 256, 0, stream>>>(w2, wt2, INTER_, DIM_);
    out_gemm2<true, false><<<dim3(DIM_/128, T_/128, E_), 256, 0, stream>>>(
        hbuf, wt2, out, obuf, aw, INTER_, counts, lslot);

    // --- shared expert path (combine with routed obuf fused in epilogue) ---
    transpose_bf16_kernel<<<dim3(SH_/64, DIM_/64, 1), 256, 0, stream>>>(sw1, swt1, DIM_, SH_);
    transpose_bf16_kernel<<<dim3(SH_/64, DIM_/64, 1), 256, 0, stream>>>(sw3, swt3, DIM_, SH_);
    swiglu_gemm2<false><<<dim3(SH_/128, T_/128), 256, 0, stream>>>(
        xb, swt1, swt3, hs, SH_, DIM_, nullptr, nullptr, nullptr);
    transpose_bf16_kernel<<<dim3(DIM_/64, SH_/64, 1), 256, 0, stream>>>(sw2, swt2, SH_, DIM_);
    out_gemm2<false, true><<<dim3(DIM_/128, T_/128), 256, 0, stream>>>(
        hs, swt2, out, obuf, aw, SH_, nullptr, nullptr);
}